// Round 1
// baseline (18292.723 us; speedup 1.0000x reference)
//
#include <hip/hip_runtime.h>

// PopulationSNN: 3-layer LIF SNN, T=100 sequential steps.
// Structure: per-sample independence => one persistent block owns BT batch
// rows for all T steps / all layers. v-state in registers, spikes in LDS.
// x is (B,N,T); we transpose once to (T,B,N) in d_ws for coalesced per-step
// tile loads (fallback to strided loads if ws too small).

#define T_STEPS 100
#define BB      2048
#define N_IN    512
#define H1S     512
#define H2S     256
#define NOUT    5
#define BT      8     // batch rows per block -> 256 blocks (1 per CU)
#define NTH     512   // threads per block (8 waves/CU, 2 per SIMD)

// ---- transpose x:(B*N, T) -> xt:(T, B*N) ----
__global__ __launch_bounds__(256)
void transpose_kernel(const float* __restrict__ x, float* __restrict__ xt) {
    __shared__ float tile[32 * 101];          // pad 101: conflict-free col reads
    const long i0 = (long)blockIdx.x * 32;    // 32 rows of length T=100
    const float4* src = (const float4*)(x + i0 * T_STEPS); // contiguous 12.8KB
    for (int f = threadIdx.x; f < 800; f += 256) {
        float4 v = src[f];
        int i  = f / 25;            // 25 float4 per row (T=100)
        int t4 = (f % 25) * 4;
        float* d = &tile[i * 101 + t4];
        d[0] = v.x; d[1] = v.y; d[2] = v.z; d[3] = v.w;
    }
    __syncthreads();
    const int lane = threadIdx.x & 31;
    const int tg   = threadIdx.x >> 5;        // 0..7
    for (int t = tg; t < T_STEPS; t += 8) {
        xt[(long)t * (BB * N_IN) + i0 + lane] = tile[lane * 101 + t];
    }
}

// ---- persistent fused SNN kernel ----
template <bool USE_XT>
__global__ __launch_bounds__(NTH)
void snn_kernel(const float* __restrict__ xsrc,
                const float* __restrict__ W1, const float* __restrict__ b1,
                const float* __restrict__ W2, const float* __restrict__ b2,
                const float* __restrict__ Wo, const float* __restrict__ bo,
                float* __restrict__ out)
{
    __shared__ float a_tile[BT * N_IN];   // 16KB  x rows for step t
    __shared__ float s1[BT * H1S];        // 16KB  layer-1 spikes
    __shared__ float s2[BT * 260];        // 8.3KB layer-2 spikes (pitch 260)
    __shared__ float woLds[NOUT * H2S];   // 5KB   Wo cached all steps
    __shared__ float part[160];           // GEMM3 partials

    const int tid = threadIdx.x;
    const int b0  = blockIdx.x * BT;

    for (int i = tid; i < NOUT * H2S; i += NTH) woLds[i] = Wo[i];

    // GEMM1 tile: 2 rows x 4 cols per thread. GEMM2: 2 rows x 2 cols.
    const int jg = tid & 127;
    const int rg = tid >> 7;              // 0..3 -> rows rg*2, rg*2+1
    const int j1 = jg * 4;
    const int j2 = jg * 2;
    const int r0 = rg * 2;

    float b1r[4], b2r[2];
#pragma unroll
    for (int jj = 0; jj < 4; ++jj) b1r[jj] = b1[j1 + jj];
    b2r[0] = b2[j2]; b2r[1] = b2[j2 + 1];

    float v1[2][4], v2[2][2];
#pragma unroll
    for (int r = 0; r < 2; ++r) {
#pragma unroll
        for (int jj = 0; jj < 4; ++jj) v1[r][jj] = 0.0f;
        v2[r][0] = 0.0f; v2[r][1] = 0.0f;
    }

    // GEMM3 roles: 160 threads compute 64-len partials; 40 threads own (r,o)
    const int ro = tid >> 2;              // 0..39 valid for tid<160
    const int cc = tid & 3;
    const int r3 = (ro < 40) ? (ro / 5) : 0;
    const int o3 = (ro < 40) ? (ro % 5) : 0;
    float vo = 0.0f, osum = 0.0f, bor = 0.0f;
    if (tid < 40) bor = bo[tid % 5];

    const float4* w1p = (const float4*)(W1 + (size_t)j1 * N_IN);
    const float4* w2p = (const float4*)(W2 + (size_t)j2 * H1S);

    for (int t = 0; t < T_STEPS; ++t) {
        // ---- stage x tile ----
        if (USE_XT) {
            const float4* src = (const float4*)(xsrc + (size_t)t * (BB * N_IN)
                                                + (size_t)b0 * N_IN);
            float4* dst = (float4*)a_tile;
#pragma unroll
            for (int f = 0; f < (BT * N_IN / 4) / NTH; ++f)   // 2 iters
                dst[tid + f * NTH] = src[tid + f * NTH];
        } else {
#pragma unroll
            for (int e = 0; e < (BT * N_IN) / NTH; ++e) {     // 8 iters
                int idx = tid + e * NTH;
                int r = idx >> 9, n = idx & 511;
                a_tile[idx] = xsrc[((size_t)(b0 + r) * N_IN + n) * T_STEPS + t];
            }
        }
        __syncthreads();

        // ---- GEMM1: h1[8][512] ----
        float acc[2][4];
#pragma unroll
        for (int r = 0; r < 2; ++r)
#pragma unroll
            for (int jj = 0; jj < 4; ++jj) acc[r][jj] = 0.0f;

        const float4* a0p = (const float4*)(a_tile + (r0 + 0) * N_IN);
        const float4* a1p = (const float4*)(a_tile + (r0 + 1) * N_IN);
#pragma unroll 2
        for (int k4 = 0; k4 < N_IN / 4; ++k4) {
            float4 a0 = a0p[k4];
            float4 a1 = a1p[k4];
#pragma unroll
            for (int jj = 0; jj < 4; ++jj) {
                float4 w = w1p[jj * (N_IN / 4) + k4];
                acc[0][jj] += a0.x * w.x + a0.y * w.y + a0.z * w.z + a0.w * w.w;
                acc[1][jj] += a1.x * w.x + a1.y * w.y + a1.z * w.z + a1.w * w.w;
            }
        }
        // LIF1 + spike store
#pragma unroll
        for (int r = 0; r < 2; ++r) {
            float4 sv;
            float* svp = (float*)&sv;
#pragma unroll
            for (int jj = 0; jj < 4; ++jj) {
                float h = acc[r][jj] + b1r[jj];
                float v = v1[r][jj];
                v = v + (h - v) * 0.5f;
                bool sp = (v >= 1.0f);
                v1[r][jj] = sp ? 0.0f : v;
                svp[jj] = sp ? 1.0f : 0.0f;
            }
            ((float4*)(s1 + (r0 + r) * H1S))[jg] = sv;
        }
        __syncthreads();

        // ---- GEMM2: h2[8][256] ----
        float acc2[2][2];
        acc2[0][0] = acc2[0][1] = acc2[1][0] = acc2[1][1] = 0.0f;
        const float4* s1p0 = (const float4*)(s1 + (r0 + 0) * H1S);
        const float4* s1p1 = (const float4*)(s1 + (r0 + 1) * H1S);
#pragma unroll 2
        for (int k4 = 0; k4 < H1S / 4; ++k4) {
            float4 a0 = s1p0[k4];
            float4 a1 = s1p1[k4];
#pragma unroll
            for (int jj = 0; jj < 2; ++jj) {
                float4 w = w2p[jj * (H1S / 4) + k4];
                acc2[0][jj] += a0.x * w.x + a0.y * w.y + a0.z * w.z + a0.w * w.w;
                acc2[1][jj] += a1.x * w.x + a1.y * w.y + a1.z * w.z + a1.w * w.w;
            }
        }
        // LIF2 + spike store
#pragma unroll
        for (int r = 0; r < 2; ++r) {
            float2 sv;
#pragma unroll
            for (int jj = 0; jj < 2; ++jj) {
                float h = acc2[r][jj] + b2r[jj];
                float v = v2[r][jj];
                v = v + (h - v) * 0.5f;
                bool sp = (v >= 1.0f);
                v2[r][jj] = sp ? 0.0f : v;
                ((float*)&sv)[jj] = sp ? 1.0f : 0.0f;
            }
            ((float2*)(s2 + (r0 + r) * 260))[jg] = sv;
        }
        __syncthreads();

        // ---- GEMM3: o[8][5], K=256 split in 4 chunks of 64 ----
        if (tid < 160) {
            const float4* s2p = (const float4*)(s2 + r3 * 260 + cc * 64);
            const float4* wop = (const float4*)(woLds + o3 * H2S + cc * 64);
            float p = 0.0f;
#pragma unroll
            for (int k = 0; k < 16; ++k) {
                float4 a = s2p[k], w = wop[k];
                p += a.x * w.x + a.y * w.y + a.z * w.z + a.w * w.w;
            }
            part[tid] = p;
        }
        __syncthreads();

        if (tid < 40) {
            float o_cur = part[tid * 4] + part[tid * 4 + 1]
                        + part[tid * 4 + 2] + part[tid * 4 + 3] + bor;
            float v = vo + (o_cur - vo) * 0.5f;
            if (v >= 1.0f) { osum += 1.0f; vo = 0.0f; }
            else           { vo = v; }
        }
        // next-iter a_tile overwrite is safe: all GEMM1 reads precede the
        // s1 barrier; s2 overwrite safe: GEMM3 reads precede part barrier.
    }

    if (tid < 40) {
        out[(size_t)(b0 + tid / 5) * NOUT + (tid % 5)] = osum / (float)T_STEPS;
    }
}

extern "C" void kernel_launch(void* const* d_in, const int* in_sizes, int n_in,
                              void* d_out, int out_size, void* d_ws, size_t ws_size,
                              hipStream_t stream) {
    const float* x  = (const float*)d_in[0];
    const float* W1 = (const float*)d_in[1];
    const float* b1 = (const float*)d_in[2];
    const float* W2 = (const float*)d_in[3];
    const float* b2 = (const float*)d_in[4];
    const float* Wo = (const float*)d_in[5];
    const float* bo = (const float*)d_in[6];
    float* out = (float*)d_out;

    const size_t xt_bytes = (size_t)T_STEPS * BB * N_IN * sizeof(float);
    if (ws_size >= xt_bytes) {
        float* xt = (float*)d_ws;
        transpose_kernel<<<(BB * N_IN) / 32, 256, 0, stream>>>(x, xt);
        snn_kernel<true><<<BB / BT, NTH, 0, stream>>>(xt, W1, b1, W2, b2, Wo, bo, out);
    } else {
        snn_kernel<false><<<BB / BT, NTH, 0, stream>>>(x, W1, b1, W2, b2, Wo, bo, out);
    }
}

// Round 2
// 2881.284 us; speedup vs baseline: 6.3488x; 6.3488x over previous
//
#include <hip/hip_runtime.h>

// PopulationSNN: 3-layer LIF SNN, T=100 sequential steps, B=2048.
// One block per CU owns 8 batch rows for all steps/layers.
// R2: weights pre-transposed to k-major in d_ws so weight loads are
// lane-coalesced (R1 was latency-bound on 8KB-strided lane scatter,
// VALUBusy 14%). Thread owns 8 rows x 4 j-cols, 4-way k-split, partials
// reduced via 64KB LDS scratch that aliases the x-tile region.

#define T_STEPS 100
#define BB      2048
#define N_IN    512
#define H1S     512
#define H2S     256
#define NOUT    5
#define BT      8
#define NTH     512

// ---- transpose x:(B*N, T) -> xt:(T, B*N) ----
__global__ __launch_bounds__(256)
void transpose_kernel(const float* __restrict__ x, float* __restrict__ xt) {
    __shared__ float tile[32 * 101];
    const long i0 = (long)blockIdx.x * 32;
    const float4* src = (const float4*)(x + i0 * T_STEPS);
    for (int f = threadIdx.x; f < 800; f += 256) {
        float4 v = src[f];
        int i  = f / 25;
        int t4 = (f % 25) * 4;
        float* d = &tile[i * 101 + t4];
        d[0] = v.x; d[1] = v.y; d[2] = v.z; d[3] = v.w;
    }
    __syncthreads();
    const int lane = threadIdx.x & 31;
    const int tg   = threadIdx.x >> 5;
    for (int t = tg; t < T_STEPS; t += 8) {
        xt[(long)t * (BB * N_IN) + i0 + lane] = tile[lane * 101 + t];
    }
}

// ---- generic 32x32 transpose: dst[c*R + r] = src[r*C + c] ----
__global__ __launch_bounds__(256)
void wtrans_kernel(const float* __restrict__ src, float* __restrict__ dst,
                   int R, int C) {
    __shared__ float tl[32][33];
    const int c0 = blockIdx.x * 32, r0 = blockIdx.y * 32;
    const int lx = threadIdx.x & 31, ly = threadIdx.x >> 5;
    for (int i = ly; i < 32; i += 8)
        tl[i][lx] = src[(size_t)(r0 + i) * C + c0 + lx];
    __syncthreads();
    for (int i = ly; i < 32; i += 8)
        dst[(size_t)(c0 + i) * R + r0 + lx] = tl[lx][i];
}

__device__ __forceinline__ void lif4(float4 h, float4& v, float4& sp) {
    v.x += (h.x - v.x) * 0.5f; v.y += (h.y - v.y) * 0.5f;
    v.z += (h.z - v.z) * 0.5f; v.w += (h.w - v.w) * 0.5f;
    sp.x = (v.x >= 1.0f) ? 1.0f : 0.0f; if (v.x >= 1.0f) v.x = 0.0f;
    sp.y = (v.y >= 1.0f) ? 1.0f : 0.0f; if (v.y >= 1.0f) v.y = 0.0f;
    sp.z = (v.z >= 1.0f) ? 1.0f : 0.0f; if (v.z >= 1.0f) v.z = 0.0f;
    sp.w = (v.w >= 1.0f) ? 1.0f : 0.0f; if (v.w >= 1.0f) v.w = 0.0f;
}

template <bool USE_XT>
__global__ __launch_bounds__(NTH, 2)
void snn_kernel(const float* __restrict__ xsrc,
                const float* __restrict__ W1t,   // (512 k, 512 j)
                const float* __restrict__ b1,
                const float* __restrict__ W2t,   // (512 k, 256 j)
                const float* __restrict__ b2,
                const float* __restrict__ Wo,    // (5, 256)
                const float* __restrict__ bo,
                float* __restrict__ out)
{
    // regA union: x-tile (4096 f) | red1 (4x8x512 f = 16384 f) | red2 (8x8x256 f)
    __shared__ float regA[16384];   // 64KB
    __shared__ float s1[4096];      // 16KB spikes L1
    __shared__ float s2[2048];      // 8KB  spikes L2
    __shared__ float woL[1280];     // 5KB  Wo cache
    __shared__ float part[320];

    const int tid = threadIdx.x;
    const int b0  = blockIdx.x * BT;

    // roles
    const int jg1 = tid & 127, kg1 = tid >> 7;   // GEMM1: j=jg1*4, k in [kg1*128,+128)
    const int jg2 = tid & 63,  kg2 = tid >> 6;   // GEMM2: j=jg2*4, k in [kg2*64,+64)
    const int rr  = tid >> 6;                    // reduce: batch row
    const int jr  = (tid & 63) * 4;              // reduce: j base (float4)
    // GEMM3 roles
    const int ro = tid >> 3, cc3 = tid & 7;
    const int r3 = ro / 5, o3 = ro - 5 * r3;     // valid tid<320
    const int rf = tid / 5, of = tid - 5 * rf;   // valid tid<40

    for (int i = tid; i < NOUT * H2S; i += NTH) woL[i] = Wo[i];

    float4 b1v[2], b2v;
    b1v[0] = *(const float4*)&b1[jr];
    b1v[1] = *(const float4*)&b1[256 + jr];
    b2v    = *(const float4*)&b2[jr];
    float4 v1[2], v2;
    v1[0] = make_float4(0.f,0.f,0.f,0.f); v1[1] = v1[0]; v2 = v1[0];
    float vo = 0.0f, osum = 0.0f, bor = (tid < 40) ? bo[of] : 0.0f;

    float4* rA4 = (float4*)regA;
    float4* s1f4 = (float4*)s1;
    float4* s2f4 = (float4*)s2;
    const float4* w1p = ((const float4*)W1t) + jg1;  // row k: k*128 float4
    const float4* w2p = ((const float4*)W2t) + jg2;  // row k: k*64 float4

    for (int t = 0; t < T_STEPS; ++t) {
        // ---- stage x tile into regA[0:4096] ----
        if (USE_XT) {
            const float4* src = (const float4*)(xsrc + (size_t)t * (BB * N_IN)
                                                + (size_t)b0 * N_IN);
            rA4[tid] = src[tid];
            rA4[tid + NTH] = src[tid + NTH];
        } else {
#pragma unroll
            for (int e = 0; e < 8; ++e) {
                int i = tid + e * NTH;
                regA[i] = xsrc[((size_t)(b0 + (i >> 9)) * N_IN + (i & 511)) * T_STEPS + t];
            }
        }
        __syncthreads();                                      // A

        // ---- GEMM1: acc[r] = sum_k a[r][k] * W1t[k][j..j+3] ----
        float4 acc[8];
#pragma unroll
        for (int r = 0; r < 8; ++r) acc[r] = make_float4(0.f,0.f,0.f,0.f);
        {
            const int kb4 = kg1 * 32;
#pragma unroll 2
            for (int k4 = 0; k4 < 32; ++k4) {
                float4 a[8];
#pragma unroll
                for (int r = 0; r < 8; ++r) a[r] = rA4[r * 128 + kb4 + k4];
                const float4* wk = w1p + (size_t)(kb4 + k4) * 512;
#define G1Q(QI, C) { float4 w = wk[QI * 128];                                   \
    _Pragma("unroll") for (int r = 0; r < 8; ++r) {                             \
        acc[r].x += a[r].C * w.x; acc[r].y += a[r].C * w.y;                     \
        acc[r].z += a[r].C * w.z; acc[r].w += a[r].C * w.w; } }
                G1Q(0, x) G1Q(1, y) G1Q(2, z) G1Q(3, w)
#undef G1Q
            }
        }
        __syncthreads();                                      // B: x-tile reads done
#pragma unroll
        for (int r = 0; r < 8; ++r) rA4[(kg1 * 8 + r) * 128 + jg1] = acc[r];
        __syncthreads();                                      // C

        // ---- reduce1 + LIF1 -> s1 ----
#pragma unroll
        for (int c = 0; c < 2; ++c) {
            float4 h = b1v[c];
#pragma unroll
            for (int kg = 0; kg < 4; ++kg) {
                float4 p = rA4[(kg * 8 + rr) * 128 + c * 64 + (tid & 63)];
                h.x += p.x; h.y += p.y; h.z += p.z; h.w += p.w;
            }
            float4 sp; lif4(h, v1[c], sp);
            s1f4[rr * 128 + c * 64 + (tid & 63)] = sp;
        }
        __syncthreads();                                      // D

        // ---- GEMM2: acc2[r] = sum_k s1[r][k] * W2t[k][j..j+3] ----
        float4 acc2[8];
#pragma unroll
        for (int r = 0; r < 8; ++r) acc2[r] = make_float4(0.f,0.f,0.f,0.f);
        {
            const int kb4 = kg2 * 16;
#pragma unroll 2
            for (int k4 = 0; k4 < 16; ++k4) {
                float4 a[8];
#pragma unroll
                for (int r = 0; r < 8; ++r) a[r] = s1f4[r * 128 + kb4 + k4];
                const float4* wk = w2p + (size_t)(kb4 + k4) * 256;
#define G2Q(QI, C) { float4 w = wk[QI * 64];                                    \
    _Pragma("unroll") for (int r = 0; r < 8; ++r) {                             \
        acc2[r].x += a[r].C * w.x; acc2[r].y += a[r].C * w.y;                   \
        acc2[r].z += a[r].C * w.z; acc2[r].w += a[r].C * w.w; } }
                G2Q(0, x) G2Q(1, y) G2Q(2, z) G2Q(3, w)
#undef G2Q
            }
        }
        // red2 store: regA last read was pre-D, safe without extra barrier
#pragma unroll
        for (int r = 0; r < 8; ++r) rA4[(kg2 * 8 + r) * 64 + jg2] = acc2[r];
        __syncthreads();                                      // E

        // ---- reduce2 + LIF2 -> s2 ----
        {
            float4 h = b2v;
#pragma unroll
            for (int kg = 0; kg < 8; ++kg) {
                float4 p = rA4[(kg * 8 + rr) * 64 + (tid & 63)];
                h.x += p.x; h.y += p.y; h.z += p.z; h.w += p.w;
            }
            float4 sp; lif4(h, v2, sp);
            s2f4[rr * 64 + (tid & 63)] = sp;
        }
        __syncthreads();                                      // F

        // ---- GEMM3: o[8][5] ----
        if (tid < 320) {
            const float4* sp2 = s2f4 + r3 * 64 + cc3 * 8;
            const float4* wo4 = ((const float4*)woL) + o3 * 64 + cc3 * 8;
            float p = 0.0f;
#pragma unroll
            for (int k = 0; k < 8; ++k) {
                float4 a = sp2[k], w = wo4[k];
                p += a.x * w.x + a.y * w.y + a.z * w.z + a.w * w.w;
            }
            part[tid] = p;
        }
        __syncthreads();                                      // G
        if (tid < 40) {
            float o_cur = bor;
#pragma unroll
            for (int i = 0; i < 8; ++i) o_cur += part[tid * 8 + i];
            float v = vo + (o_cur - vo) * 0.5f;
            if (v >= 1.0f) { osum += 1.0f; vo = 0.0f; }
            else           { vo = v; }
        }
        // next-iter staging overwrites regA: last regA reads were pre-F. safe.
    }

    if (tid < 40) out[(size_t)(b0 + rf) * NOUT + of] = osum / (float)T_STEPS;
}

extern "C" void kernel_launch(void* const* d_in, const int* in_sizes, int n_in,
                              void* d_out, int out_size, void* d_ws, size_t ws_size,
                              hipStream_t stream) {
    const float* x  = (const float*)d_in[0];
    const float* W1 = (const float*)d_in[1];
    const float* b1 = (const float*)d_in[2];
    const float* W2 = (const float*)d_in[3];
    const float* b2 = (const float*)d_in[4];
    const float* Wo = (const float*)d_in[5];
    const float* bo = (const float*)d_in[6];
    float* out = (float*)d_out;

    const size_t xt_elems = (size_t)T_STEPS * BB * N_IN;
    const size_t w1t_elems = (size_t)H1S * N_IN;
    const size_t w2t_elems = (size_t)H2S * H1S;
    const size_t full_bytes = (xt_elems + w1t_elems + w2t_elems) * sizeof(float);
    const size_t wt_bytes   = (w1t_elems + w2t_elems) * sizeof(float);

    if (ws_size >= full_bytes) {
        float* xt  = (float*)d_ws;
        float* w1t = xt + xt_elems;
        float* w2t = w1t + w1t_elems;
        transpose_kernel<<<(BB * N_IN) / 32, 256, 0, stream>>>(x, xt);
        wtrans_kernel<<<dim3(N_IN / 32, H1S / 32), 256, 0, stream>>>(W1, w1t, H1S, N_IN);
        wtrans_kernel<<<dim3(H1S / 32, H2S / 32), 256, 0, stream>>>(W2, w2t, H2S, H1S);
        snn_kernel<true><<<BB / BT, NTH, 0, stream>>>(xt, w1t, b1, w2t, b2, Wo, bo, out);
    } else {
        // ws too small for xt: transpose only weights, strided x loads
        float* w1t = (float*)d_ws;
        float* w2t = w1t + w1t_elems;
        (void)wt_bytes;
        wtrans_kernel<<<dim3(N_IN / 32, H1S / 32), 256, 0, stream>>>(W1, w1t, H1S, N_IN);
        wtrans_kernel<<<dim3(H1S / 32, H2S / 32), 256, 0, stream>>>(W2, w2t, H2S, H1S);
        snn_kernel<false><<<BB / BT, NTH, 0, stream>>>(x, w1t, b1, w2t, b2, Wo, bo, out);
    }
}